// Round 3
// baseline (417.741 us; speedup 1.0000x reference)
//
#include <hip/hip_runtime.h>
#include <math.h>

#define BB 32
#define TQQ 2000
#define TKK 512
#define CR 8            // rows (time steps) per chunk
#define RS 8            // ring slots, in chunks
#define NW 8            // 1 DP wave + 7 producer waves
#define SLOT_F 520      // floats per row slot: p[0..511], pb at 512, pad to 520

__device__ __forceinline__ float dpp_mv_111(float x, float old) {
    return __int_as_float(__builtin_amdgcn_update_dpp(__float_as_int(old), __float_as_int(x), 0x111, 0xf, 0xf, false));
}
__device__ __forceinline__ float dpp_mv_112(float x, float old) {
    return __int_as_float(__builtin_amdgcn_update_dpp(__float_as_int(old), __float_as_int(x), 0x112, 0xf, 0xf, false));
}
__device__ __forceinline__ float dpp_mv_114(float x, float old) {
    return __int_as_float(__builtin_amdgcn_update_dpp(__float_as_int(old), __float_as_int(x), 0x114, 0xf, 0xf, false));
}
__device__ __forceinline__ float dpp_mv_118(float x, float old) {
    return __int_as_float(__builtin_amdgcn_update_dpp(__float_as_int(old), __float_as_int(x), 0x118, 0xf, 0xf, false));
}
__device__ __forceinline__ float dpp_mv_b15(float x, float old) {
    return __int_as_float(__builtin_amdgcn_update_dpp(__float_as_int(old), __float_as_int(x), 0x142, 0xf, 0xf, false));
}
__device__ __forceinline__ float dpp_mv_b31(float x, float old) {
    return __int_as_float(__builtin_amdgcn_update_dpp(__float_as_int(old), __float_as_int(x), 0x143, 0xf, 0xf, false));
}
__device__ __forceinline__ float dpp_wave_shr1(float x, float old) {
    return __int_as_float(__builtin_amdgcn_update_dpp(__float_as_int(old), __float_as_int(x), 0x138, 0xf, 0xf, false));
}

__device__ __forceinline__ float wred_max(float x) {
    x = fmaxf(x, dpp_mv_111(x, -1e38f));
    x = fmaxf(x, dpp_mv_112(x, -1e38f));
    x = fmaxf(x, dpp_mv_114(x, -1e38f));
    x = fmaxf(x, dpp_mv_118(x, -1e38f));
    x = fmaxf(x, dpp_mv_b15(x, -1e38f));
    x = fmaxf(x, dpp_mv_b31(x, -1e38f));
    return __int_as_float(__builtin_amdgcn_readlane(__float_as_int(x), 63));
}
__device__ __forceinline__ float wred_sum(float x) {
    x += dpp_mv_111(x, 0.0f);
    x += dpp_mv_112(x, 0.0f);
    x += dpp_mv_114(x, 0.0f);
    x += dpp_mv_118(x, 0.0f);
    x += dpp_mv_b15(x, 0.0f);
    x += dpp_mv_b31(x, 0.0f);
    return __int_as_float(__builtin_amdgcn_readlane(__float_as_int(x), 63));
}

__device__ __forceinline__ float pow2i(int e) {    // e in [-126, 127]
    return __int_as_float((unsigned)(e + 127) << 23);
}

// one DP step over 4 state-pairs; uses OLD O[i-1] (descending order).
// Folded CTC transitions: t = E+O_prev serves as (p0+p1) for the odd state's
// skip and as the even state's pre-multiply sum.
__device__ __forceinline__ void step_quad(float4 p, float pb, float o_prev,
                                          float E[4], float O[4]) {
    float t3 = E[3] + O[2];  O[3] = (O[3] + t3) * p.w;  E[3] = t3 * pb;
    float t2 = E[2] + O[1];  O[2] = (O[2] + t2) * p.z;  E[2] = t2 * pb;
    float t1 = E[1] + O[0];  O[1] = (O[1] + t1) * p.y;  E[1] = t1 * pb;
    float t0 = E[0] + o_prev; O[0] = (O[0] + t0) * p.x; E[0] = t0 * pb;
}

// ---------------------------------------------------------------------------
// Fused kernel, v3: ONE DP wave owning all 512 pairs (8 per lane: low quad
// 4*lane.. and high quad 256+4*lane..) + 7 softmax producer waves.
// No inter-DP-wave handshake: the 255|256 boundary is a readlane, e512 is
// in-wave, and a single unified power-of-2 rescale replaces the ef0/ef1
// exchange protocol of the previous 2-wave design.
// ---------------------------------------------------------------------------
__global__ __launch_bounds__(NW * 64)
void ForwardSumLoss_77378130805413_kernel(const float* __restrict__ attn,
                                          const int* __restrict__ in_lens,
                                          const int* __restrict__ out_lens,
                                          float* __restrict__ out)
{
    __shared__ float s_slots[RS * CR * SLOT_F];   // 133120 B
    __shared__ float s_dumpE[513];
    __shared__ float s_dumpO[512];
    __shared__ int   s_ready[RS];
    __shared__ int   s_w0;
    __shared__ int   s_ec;

    const int b    = blockIdx.x;
    const int tid  = threadIdx.x;
    const int wave = tid >> 6;
    const int lane = tid & 63;

    int kl = in_lens[b];  kl = kl < 1 ? 1 : (kl > TKK ? TKK : kl);
    int ql = out_lens[b]; ql = ql < 1 ? 1 : (ql > TQQ ? TQQ : ql);
    const int nchunks = (ql + CR - 1) / CR;

    if (tid < RS)  s_ready[tid] = -1;
    if (tid == 32) s_w0 = -1;
    __syncthreads();

    volatile int* vready = s_ready;
    volatile int* vw0    = &s_w0;

    const float T = 1.0995116e12f;   // 2^40

    if (wave == 0) {
        // ------------- single DP wave: all pairs m = 0..511 + top blank -------------
        __builtin_amdgcn_s_setprio(3);
        float El[4] = {0,0,0,0}, Ol[4] = {0,0,0,0};   // pairs 4*lane + i
        float Eh[4] = {0,0,0,0}, Oh[4] = {0,0,0,0};   // pairs 256 + 4*lane + i
        float e512 = 0.f;                              // top blank (lane 63 holds truth)
        int ec = 0;                                    // cumulative 2^-ec scale
        const int b4 = 4 * lane;
        int rdyN = -9;

        for (int k = 0; k < nchunks; ++k) {
            const int t0   = k * CR;
            const int rows = min(ql - t0, CR);
            if (rdyN != k) { while (vready[k & (RS - 1)] != k) {} }
            asm volatile("" ::: "memory");
            const float* bp = s_slots + (size_t)(k & (RS - 1)) * CR * SLOT_F;

            if (rows == CR) {
                float4 PL[CR], PH[CR]; float PB[CR];
                #pragma unroll
                for (int r = 0; r < CR; ++r) {
                    PL[r] = *(const float4*)(bp + r * SLOT_F + b4);
                    PH[r] = *(const float4*)(bp + r * SLOT_F + 256 + b4);
                    PB[r] = bp[r * SLOT_F + 512];
                }
                // all of chunk k now in registers: free the slot immediately
                asm volatile("s_waitcnt lgkmcnt(0)" ::: "memory");
                if (lane == 0) *vw0 = k;
                rdyN = vready[(k + 1) & (RS - 1)];   // early probe
                #pragma unroll
                for (int r = 0; r < CR; ++r) {
                    if (k == 0 && r == 0) {
                        El[0] = (lane == 0) ? PB[0]  * T : 0.f;
                        Ol[0] = (lane == 0) ? PL[0].x * T : 0.f;
                        // high pairs and e512 stay exactly zero at t=0
                    } else {
                        float olo3 = Ol[3], ohi3 = Oh[3];
                        float o_lo = dpp_wave_shr1(olo3, 0.0f);
                        float o_hi = dpp_wave_shr1(ohi3, 0.0f);
                        float bl = __int_as_float(__builtin_amdgcn_readlane(__float_as_int(olo3), 63));
                        o_hi = (lane == 0) ? bl : o_hi;          // pair 256 <- O[255]
                        float te = e512 + ohi3; e512 = te * PB[r]; // lane63: state 1023 -> 1024
                        step_quad(PH[r], PB[r], o_hi, Eh, Oh);
                        step_quad(PL[r], PB[r], o_lo, El, Ol);
                    }
                }
                // unified rescale by power of 2 from current global max
                float m0 = fmaxf(fmaxf(fmaxf(El[0], El[1]), fmaxf(El[2], El[3])),
                                 fmaxf(fmaxf(Ol[0], Ol[1]), fmaxf(Ol[2], Ol[3])));
                float m1 = fmaxf(fmaxf(fmaxf(Eh[0], Eh[1]), fmaxf(Eh[2], Eh[3])),
                                 fmaxf(fmaxf(Oh[0], Oh[1]), fmaxf(Oh[2], Oh[3])));
                m0 = fmaxf(m0, m1);
                m0 = fmaxf(m0, (lane == 63) ? e512 : 0.f);
                m0 = wred_max(m0);
                int ef = 0;
                if (m0 > 0.f) ef = 167 - (int)((__float_as_uint(m0) >> 23) & 255);
                float fh = pow2i(ef - (ef >> 1));
                float fl = pow2i(ef >> 1);
                #pragma unroll
                for (int i = 0; i < 4; ++i) {
                    El[i] = (El[i] * fh) * fl; Ol[i] = (Ol[i] * fh) * fl;
                    Eh[i] = (Eh[i] * fh) * fl; Oh[i] = (Oh[i] * fh) * fl;
                }
                e512 = (e512 * fh) * fl;
                ec += ef;
            } else {
                for (int r = 0; r < rows; ++r) {
                    const float* sq = bp + r * SLOT_F;
                    float4 pl = *(const float4*)(sq + b4);
                    float4 ph = *(const float4*)(sq + 256 + b4);
                    float pb = sq[512];
                    if (k == 0 && r == 0) {
                        El[0] = (lane == 0) ? pb   * T : 0.f;
                        Ol[0] = (lane == 0) ? pl.x * T : 0.f;
                    } else {
                        float olo3 = Ol[3], ohi3 = Oh[3];
                        float o_lo = dpp_wave_shr1(olo3, 0.0f);
                        float o_hi = dpp_wave_shr1(ohi3, 0.0f);
                        float bl = __int_as_float(__builtin_amdgcn_readlane(__float_as_int(olo3), 63));
                        o_hi = (lane == 0) ? bl : o_hi;
                        float te = e512 + ohi3; e512 = te * pb;
                        step_quad(ph, pb, o_hi, Eh, Oh);
                        step_quad(pl, pb, o_lo, El, Ol);
                    }
                }
                asm volatile("" ::: "memory");
                if (lane == 0) *vw0 = k;
            }
        }
        #pragma unroll
        for (int i = 0; i < 4; ++i) {
            s_dumpE[b4 + i]       = El[i];
            s_dumpO[b4 + i]       = Ol[i];
            s_dumpE[256 + b4 + i] = Eh[i];
            s_dumpO[256 + b4 + i] = Oh[i];
        }
        if (lane == 63) s_dumpE[512] = e512;
        if (lane == 0)  s_ec = ec;
    } else {
        // ------------- producer waves (7): softmax one chunk each -------------
        const int pidx = wave - 1;                  // 0..6
        const float* base = attn + (size_t)b * TQQ * TKK;
        const int j0 = 8 * lane;

        for (int c = pidx; c < nchunks; c += NW - 1) {
            const int t0 = c * CR;
            while (*vw0 < c - RS) { __builtin_amdgcn_s_sleep(4); }   // slot freed by DP wave
            asm volatile("" ::: "memory");

            float4 x0[CR], x1[CR];
            #pragma unroll
            for (int r = 0; r < CR; ++r) {
                x0[r] = make_float4(-1e30f, -1e30f, -1e30f, -1e30f);
                x1[r] = x0[r];
                const int t = t0 + r;
                if (t < ql) {
                    const float* row = base + (size_t)t * TKK;
                    if (j0 < kl)     x0[r] = *(const float4*)(row + j0);
                    if (j0 + 4 < kl) x1[r] = *(const float4*)(row + j0 + 4);
                }
            }
            float* bp = s_slots + (size_t)(c & (RS - 1)) * CR * SLOT_F;
            #pragma unroll
            for (int r = 0; r < CR; ++r) {
                const int t = t0 + r;
                if (t >= ql) continue;
                float va[8] = {x0[r].x, x0[r].y, x0[r].z, x0[r].w,
                               x1[r].x, x1[r].y, x1[r].z, x1[r].w};
                float m = -1.0f;  // blank logprob
                #pragma unroll
                for (int cc = 0; cc < 8; ++cc) if (j0 + cc < kl) m = fmaxf(m, va[cc]);
                m = wred_max(m);
                float pv[8]; float vsum = 0.f;
                #pragma unroll
                for (int cc = 0; cc < 8; ++cc) {
                    pv[cc] = (j0 + cc < kl) ? __expf(va[cc] - m) : 0.f;
                    vsum += pv[cc];
                }
                vsum = wred_sum(vsum);
                float vb   = __expf(-1.0f - m);
                float rinv = 1.0f / (vsum + vb);
                float* sp = bp + (size_t)r * SLOT_F;
                *(float4*)(sp + j0)     = make_float4(pv[0]*rinv, pv[1]*rinv, pv[2]*rinv, pv[3]*rinv);
                *(float4*)(sp + j0 + 4) = make_float4(pv[4]*rinv, pv[5]*rinv, pv[6]*rinv, pv[7]*rinv);
                if (lane == 0) sp[512] = vb * rinv;
            }
            __threadfence_block();
            if (lane == 0) vready[c & (RS - 1)] = c;
        }
    }

    __syncthreads();
    if (tid == 0) {
        const double logTd = 27.725887222397812;   // 40*ln2
        const double LN2d  = 0.69314718055994531;
        float aE = s_dumpE[kl];          // even end state 2*kl (pair kl E / e512)
        float aO = s_dumpO[kl - 1];      // odd end state 2*kl-1
        int ec = s_ec;
        double sC = logTd + (double)ec * LN2d;
        double lE = (aE > 0.f) ? log((double)aE) - sC : -1e300;
        double lO = (aO > 0.f) ? log((double)aO) - sC : -1e300;
        double mx = fmax(lE, lO);
        double ll = (mx < -1e290) ? -745.0 : mx + log(exp(lE - mx) + exp(lO - mx));
        float val = (float)(-ll / ((double)kl * (double)BB));
        atomicAdd(out, val);
    }
}

extern "C" void kernel_launch(void* const* d_in, const int* in_sizes, int n_in,
                              void* d_out, int out_size, void* d_ws, size_t ws_size,
                              hipStream_t stream) {
    const float* attn     = (const float*)d_in[0];
    const int*   in_lens  = (const int*)d_in[1];
    const int*   out_lens = (const int*)d_in[2];
    float* out = (float*)d_out;
    hipMemsetAsync(out, 0, sizeof(float), stream);
    hipLaunchKernelGGL(ForwardSumLoss_77378130805413_kernel,
                       dim3(BB), dim3(NW * 64), 0, stream,
                       attn, in_lens, out_lens, out);
}

// Round 4
// 396.298 us; speedup vs baseline: 1.0541x; 1.0541x over previous
//
#include <hip/hip_runtime.h>
#include <math.h>

#define BB 32
#define TQQ 2000
#define TKK 512
#define CR 8            // rows (time steps) per chunk
#define RS 8            // ring slots, in chunks
#define NW 8            // 2 DP waves + 6 producer waves
#define SLOT_F 520      // floats per row slot: p[0..511], pb at 512, pad to 520
#define BRN 32          // boundary ring entries (4 chunks)

__device__ __forceinline__ float dpp_mv_111(float x, float old) {
    return __int_as_float(__builtin_amdgcn_update_dpp(__float_as_int(old), __float_as_int(x), 0x111, 0xf, 0xf, false));
}
__device__ __forceinline__ float dpp_mv_112(float x, float old) {
    return __int_as_float(__builtin_amdgcn_update_dpp(__float_as_int(old), __float_as_int(x), 0x112, 0xf, 0xf, false));
}
__device__ __forceinline__ float dpp_mv_114(float x, float old) {
    return __int_as_float(__builtin_amdgcn_update_dpp(__float_as_int(old), __float_as_int(x), 0x114, 0xf, 0xf, false));
}
__device__ __forceinline__ float dpp_mv_118(float x, float old) {
    return __int_as_float(__builtin_amdgcn_update_dpp(__float_as_int(old), __float_as_int(x), 0x118, 0xf, 0xf, false));
}
__device__ __forceinline__ float dpp_mv_b15(float x, float old) {
    return __int_as_float(__builtin_amdgcn_update_dpp(__float_as_int(old), __float_as_int(x), 0x142, 0xf, 0xf, false));
}
__device__ __forceinline__ float dpp_mv_b31(float x, float old) {
    return __int_as_float(__builtin_amdgcn_update_dpp(__float_as_int(old), __float_as_int(x), 0x143, 0xf, 0xf, false));
}
__device__ __forceinline__ float dpp_wave_shr1(float x, float old) {
    return __int_as_float(__builtin_amdgcn_update_dpp(__float_as_int(old), __float_as_int(x), 0x138, 0xf, 0xf, false));
}

__device__ __forceinline__ float wred_max(float x) {
    x = fmaxf(x, dpp_mv_111(x, -1e38f));
    x = fmaxf(x, dpp_mv_112(x, -1e38f));
    x = fmaxf(x, dpp_mv_114(x, -1e38f));
    x = fmaxf(x, dpp_mv_118(x, -1e38f));
    x = fmaxf(x, dpp_mv_b15(x, -1e38f));
    x = fmaxf(x, dpp_mv_b31(x, -1e38f));
    return __int_as_float(__builtin_amdgcn_readlane(__float_as_int(x), 63));
}
__device__ __forceinline__ float wred_sum(float x) {
    x += dpp_mv_111(x, 0.0f);
    x += dpp_mv_112(x, 0.0f);
    x += dpp_mv_114(x, 0.0f);
    x += dpp_mv_118(x, 0.0f);
    x += dpp_mv_b15(x, 0.0f);
    x += dpp_mv_b31(x, 0.0f);
    return __int_as_float(__builtin_amdgcn_readlane(__float_as_int(x), 63));
}

__device__ __forceinline__ float pow2i(int e) {    // e in [-126, 127]
    return __int_as_float((unsigned)(e + 127) << 23);
}

// one DP step over 4 state-pairs/lane; uses OLD O[i-1] (descending order)
__device__ __forceinline__ void step_quad(float4 p, float pb, float o_prev,
                                          float E[4], float O[4]) {
    float t3 = E[3] + O[2];  O[3] = (O[3] + t3) * p.w;  E[3] = t3 * pb;
    float t2 = E[2] + O[1];  O[2] = (O[2] + t2) * p.z;  E[2] = t2 * pb;
    float t1 = E[1] + O[0];  O[1] = (O[1] + t1) * p.y;  E[1] = t1 * pb;
    float t0 = E[0] + o_prev; O[0] = (O[0] + t0) * p.x; E[0] = t0 * pb;
}

// load one chunk's fragment (8 rows x float4 + pb) into register buffer
#define LOADCK(PP, BBf, kk) do {                                              \
    const float* bp_ = s_slots + (size_t)((kk) & (RS - 1)) * CR * SLOT_F;     \
    _Pragma("unroll")                                                         \
    for (int r_ = 0; r_ < CR; ++r_) {                                         \
        PP[r_]  = *(const float4*)(bp_ + r_ * SLOT_F + base4);                \
        BBf[r_] = bp_[r_ * SLOT_F + 512];                                     \
    } } while (0)

// ---------------------------------------------------------------------------
// Fused kernel v4: the proven 2-DP-wave pipeline (222us baseline) plus
// one-chunk-ahead REGISTER prefetch in both DP waves and cached gate probes,
// so the per-chunk LDS load latency and flag polls overlap the previous
// chunk's compute instead of serializing with it.
// ---------------------------------------------------------------------------
__global__ __launch_bounds__(NW * 64)
void ForwardSumLoss_77378130805413_kernel(const float* __restrict__ attn,
                                          const int* __restrict__ in_lens,
                                          const int* __restrict__ out_lens,
                                          float* __restrict__ out)
{
    __shared__ float s_slots[RS * CR * SLOT_F];   // 133120 B
    __shared__ float s_dumpE[513];
    __shared__ float s_dumpO[512];
    __shared__ float s_bring[BRN];                // boundary O[255](t) ring, wave0 scale
    __shared__ int   s_ef0[4];                    // wave0 per-chunk exponent ring
    __shared__ int   s_ready[RS];
    __shared__ int   s_w0, s_w1;
    __shared__ int   s_e0c, s_e1c;                // final cumulative exponents

    const int b    = blockIdx.x;
    const int tid  = threadIdx.x;
    const int wave = tid >> 6;
    const int lane = tid & 63;

    int kl = in_lens[b];  kl = kl < 1 ? 1 : (kl > TKK ? TKK : kl);
    int ql = out_lens[b]; ql = ql < 1 ? 1 : (ql > TQQ ? TQQ : ql);
    const int nchunks = (ql + CR - 1) / CR;

    if (tid < RS)  s_ready[tid] = -1;
    if (tid < BRN) s_bring[tid] = 0.f;
    if (tid == 32) s_w0 = -1;
    if (tid == 33) s_w1 = -1;
    __syncthreads();

    volatile int* vready = s_ready;
    volatile int* vw0    = &s_w0;
    volatile int* vw1    = &s_w1;
    volatile int* vEF0   = s_ef0;

    const float T = 1.0995116e12f;   // 2^40

    if (wave == 0) {
        // ------------- DP wave 0: state pairs m = 0..255 (m = 4*lane + i) -------------
        __builtin_amdgcn_s_setprio(3);
        float E[4] = {0,0,0,0}, O[4] = {0,0,0,0};
        int e0c = 0;
        const int base4 = 4 * lane;
        int rdyN = -9, w1s = -9;

        float4 Pa[CR], Pb[CR]; float Ba[CR], Bb[CR];

// compute chunk k from buffer (PP,BBf); publishes bring ring, EF0, vw0
#define COMPUTE0(PP, BBf)                                                     \
    do {                                                                      \
        if (rows == CR) {                                                     \
            _Pragma("unroll")                                                 \
            for (int r = 0; r < CR; ++r) {                                    \
                if (k == 0 && r == 0) {                                       \
                    E[0] = (lane == 0) ? BBf[0]  * T : 0.f;                   \
                    O[0] = (lane == 0) ? PP[0].x * T : 0.f;                   \
                } else {                                                      \
                    float o_prev = dpp_wave_shr1(O[3], 0.0f);                 \
                    step_quad(PP[r], BBf[r], o_prev, E, O);                   \
                }                                                             \
                if (r < CR - 1) { if (lane == 63) s_bring[(t0 + r) & (BRN - 1)] = O[3]; } \
            }                                                                 \
            float m0 = fmaxf(fmaxf(fmaxf(E[0], E[1]), fmaxf(E[2], E[3])),    \
                             fmaxf(fmaxf(O[0], O[1]), fmaxf(O[2], O[3])));    \
            m0 = wred_max(m0);                                                \
            int ef = 0;                                                       \
            if (m0 > 0.f) ef = 167 - (int)((__float_as_uint(m0) >> 23) & 255);\
            float fh = pow2i(ef - (ef >> 1));                                 \
            float fl = pow2i(ef >> 1);                                        \
            _Pragma("unroll")                                                 \
            for (int i = 0; i < 4; ++i) { E[i] = (E[i]*fh)*fl; O[i] = (O[i]*fh)*fl; } \
            e0c += ef;                                                        \
            if (lane == 0) vEF0[k & 3] = ef;                                  \
            if (lane == 63) s_bring[(t0 + CR - 1) & (BRN - 1)] = O[3];        \
        } else {                                                              \
            _Pragma("unroll")                                                 \
            for (int r = 0; r < CR; ++r) {                                    \
                if (r < rows) {                                               \
                    if (k == 0 && r == 0) {                                   \
                        E[0] = (lane == 0) ? BBf[0]  * T : 0.f;               \
                        O[0] = (lane == 0) ? PP[0].x * T : 0.f;               \
                    } else {                                                  \
                        float o_prev = dpp_wave_shr1(O[3], 0.0f);             \
                        step_quad(PP[r], BBf[r], o_prev, E, O);               \
                    }                                                         \
                    if (lane == 63) s_bring[(t0 + r) & (BRN - 1)] = O[3];     \
                }                                                             \
            }                                                                 \
        }                                                                     \
        asm volatile("" ::: "memory");                                        \
        if (lane == 0) *vw0 = k;                                              \
    } while (0)

        while (vready[0] != 0) {}
        asm volatile("" ::: "memory");
        LOADCK(Pa, Ba, 0);

        int k = 0;
        for (;;) {
            {   // phase A: compute k from (Pa,Ba), prefetch k+1 into (Pb,Bb)
                const int t0   = k * CR;
                const int rows = min(ql - t0, CR);
                if (k + 1 < nchunks) {
                    if (rdyN != k + 1) { while (vready[(k + 1) & (RS - 1)] != k + 1) {} }
                    asm volatile("" ::: "memory");
                    LOADCK(Pb, Bb, k + 1);
                }
                if (k >= 2 && w1s < k - 2) { while (w1s < k - 2) { w1s = *vw1; } }
                asm volatile("" ::: "memory");
                COMPUTE0(Pa, Ba);
                w1s  = *vw1;                             // end probes (cached gates)
                rdyN = vready[(k + 2) & (RS - 1)];
            }
            if (++k >= nchunks) break;
            {   // phase B: compute k from (Pb,Bb), prefetch k+1 into (Pa,Ba)
                const int t0   = k * CR;
                const int rows = min(ql - t0, CR);
                if (k + 1 < nchunks) {
                    if (rdyN != k + 1) { while (vready[(k + 1) & (RS - 1)] != k + 1) {} }
                    asm volatile("" ::: "memory");
                    LOADCK(Pa, Ba, k + 1);
                }
                if (k >= 2 && w1s < k - 2) { while (w1s < k - 2) { w1s = *vw1; } }
                asm volatile("" ::: "memory");
                COMPUTE0(Pb, Bb);
                w1s  = *vw1;
                rdyN = vready[(k + 2) & (RS - 1)];
            }
            if (++k >= nchunks) break;
        }
#undef COMPUTE0
        #pragma unroll
        for (int i = 0; i < 4; ++i) {
            s_dumpE[base4 + i] = E[i];
            s_dumpO[base4 + i] = O[i];
        }
        if (lane == 0) s_e0c = e0c;
    } else if (wave == 1) {
        // ------------- DP wave 1: pairs m = 256..511 + top blank (e512) -------------
        __builtin_amdgcn_s_setprio(3);
        float E[4] = {0,0,0,0}, O[4] = {0,0,0,0}, e512 = 0.f;
        int e0c = 0, e1c = 0;
        const int base4 = 256 + 4 * lane;
        int rdyN = -9, w0s = -9;

        float4 Pa[CR], Pb[CR]; float Ba[CR], Bb[CR];

#define COMPUTE1(PP, BBf)                                                     \
    do {                                                                      \
        int dE = e1c - e0c;                                                   \
        dE = dE < -250 ? -250 : (dE > 250 ? 250 : dE);                        \
        const float Ch = pow2i(dE - (dE >> 1));                               \
        const float Cl = pow2i(dE >> 1);                                      \
        if (rows == CR) {                                                     \
            int ef0k = vEF0[k & 3];             /* valid: w0s >= k */         \
            float BND[CR];                                                    \
            _Pragma("unroll")                                                 \
            for (int r = 0; r < CR; ++r)                                      \
                BND[r] = (s_bring[(t0 - 1 + r) & (BRN - 1)] * Ch) * Cl;       \
            _Pragma("unroll")                                                 \
            for (int r = 0; r < CR; ++r) {                                    \
                float o_prev = dpp_wave_shr1(O[3], 0.0f);                     \
                o_prev = (lane == 0) ? BND[r] : o_prev;                       \
                float te = e512 + O[3]; e512 = te * BBf[r];                   \
                step_quad(PP[r], BBf[r], o_prev, E, O);                       \
            }                                                                 \
            float m1 = fmaxf(fmaxf(fmaxf(E[0], E[1]), fmaxf(E[2], E[3])),    \
                             fmaxf(fmaxf(O[0], O[1]), fmaxf(O[2], O[3])));    \
            m1 = fmaxf(m1, e512);                                             \
            m1 = wred_max(m1);                                                \
            int ef1 = (m1 > 0.f) ? (167 - (int)((__float_as_uint(m1) >> 23) & 255)) \
                                 : ef0k;                                      \
            float fh = pow2i(ef1 - (ef1 >> 1));                               \
            float fl = pow2i(ef1 >> 1);                                       \
            _Pragma("unroll")                                                 \
            for (int i = 0; i < 4; ++i) { E[i] = (E[i]*fh)*fl; O[i] = (O[i]*fh)*fl; } \
            e512 = (e512 * fh) * fl;                                          \
            e1c += ef1;                                                       \
            e0c += ef0k;                                                      \
        } else {                                                              \
            _Pragma("unroll")                                                 \
            for (int r = 0; r < CR; ++r) {                                    \
                if (r < rows) {                                               \
                    float bnd = (s_bring[(t0 - 1 + r) & (BRN - 1)] * Ch) * Cl;\
                    float o_prev = dpp_wave_shr1(O[3], 0.0f);                 \
                    o_prev = (lane == 0) ? bnd : o_prev;                      \
                    float te = e512 + O[3]; e512 = te * BBf[r];               \
                    step_quad(PP[r], BBf[r], o_prev, E, O);                   \
                }                                                             \
            }                                                                 \
        }                                                                     \
        asm volatile("" ::: "memory");                                        \
        if (lane == 0) *vw1 = k;                                              \
    } while (0)

        while (vready[0] != 0) {}
        asm volatile("" ::: "memory");
        LOADCK(Pa, Ba, 0);

        int k = 0;
        for (;;) {
            {   // phase A
                const int t0   = k * CR;
                const int rows = min(ql - t0, CR);
                if (k + 1 < nchunks) {
                    if (rdyN != k + 1) { while (vready[(k + 1) & (RS - 1)] != k + 1) {} }
                    asm volatile("" ::: "memory");
                    LOADCK(Pb, Bb, k + 1);
                }
                if (w0s < k) { while (w0s < k) { w0s = *vw0; } }
                asm volatile("" ::: "memory");
                COMPUTE1(Pa, Ba);
                w0s  = *vw0;                             // end probes
                rdyN = vready[(k + 2) & (RS - 1)];
            }
            if (++k >= nchunks) break;
            {   // phase B
                const int t0   = k * CR;
                const int rows = min(ql - t0, CR);
                if (k + 1 < nchunks) {
                    if (rdyN != k + 1) { while (vready[(k + 1) & (RS - 1)] != k + 1) {} }
                    asm volatile("" ::: "memory");
                    LOADCK(Pa, Ba, k + 1);
                }
                if (w0s < k) { while (w0s < k) { w0s = *vw0; } }
                asm volatile("" ::: "memory");
                COMPUTE1(Pb, Bb);
                w0s  = *vw0;
                rdyN = vready[(k + 2) & (RS - 1)];
            }
            if (++k >= nchunks) break;
        }
#undef COMPUTE1
        #pragma unroll
        for (int i = 0; i < 4; ++i) {
            s_dumpE[base4 + i] = E[i];
            s_dumpO[base4 + i] = O[i];
        }
        if (lane == 63) s_dumpE[512] = e512;
        if (lane == 0)  s_e1c = e1c;
    } else {
        // ------------- producer waves (6): softmax one chunk each -------------
        const int pidx = wave - 2;                  // 0..5
        const float* base = attn + (size_t)b * TQQ * TKK;
        const int j0 = 8 * lane;

        for (int c = pidx; c < nchunks; c += NW - 2) {
            const int t0 = c * CR;
            while (*vw1 < c - RS) { __builtin_amdgcn_s_sleep(4); }   // slot freed by wave1
            asm volatile("" ::: "memory");

            float4 x0[CR], x1[CR];
            #pragma unroll
            for (int r = 0; r < CR; ++r) {
                x0[r] = make_float4(-1e30f, -1e30f, -1e30f, -1e30f);
                x1[r] = x0[r];
                const int t = t0 + r;
                if (t < ql) {
                    const float* row = base + (size_t)t * TKK;
                    if (j0 < kl)     x0[r] = *(const float4*)(row + j0);
                    if (j0 + 4 < kl) x1[r] = *(const float4*)(row + j0 + 4);
                }
            }
            float* bp = s_slots + (size_t)(c & (RS - 1)) * CR * SLOT_F;
            #pragma unroll
            for (int r = 0; r < CR; ++r) {
                const int t = t0 + r;
                if (t >= ql) continue;
                float va[8] = {x0[r].x, x0[r].y, x0[r].z, x0[r].w,
                               x1[r].x, x1[r].y, x1[r].z, x1[r].w};
                float m = -1.0f;  // blank logprob
                #pragma unroll
                for (int cc = 0; cc < 8; ++cc) if (j0 + cc < kl) m = fmaxf(m, va[cc]);
                m = wred_max(m);
                float pv[8]; float vsum = 0.f;
                #pragma unroll
                for (int cc = 0; cc < 8; ++cc) {
                    pv[cc] = (j0 + cc < kl) ? __expf(va[cc] - m) : 0.f;
                    vsum += pv[cc];
                }
                vsum = wred_sum(vsum);
                float vb   = __expf(-1.0f - m);
                float rinv = 1.0f / (vsum + vb);
                float* sp = bp + (size_t)r * SLOT_F;
                *(float4*)(sp + j0)     = make_float4(pv[0]*rinv, pv[1]*rinv, pv[2]*rinv, pv[3]*rinv);
                *(float4*)(sp + j0 + 4) = make_float4(pv[4]*rinv, pv[5]*rinv, pv[6]*rinv, pv[7]*rinv);
                if (lane == 0) sp[512] = vb * rinv;
            }
            __threadfence_block();
            if (lane == 0) vready[c & (RS - 1)] = c;
        }
    }

    __syncthreads();
    if (tid == 0) {
        const double logTd = 27.725887222397812;   // 40*ln2
        const double LN2d  = 0.69314718055994531;
        float aE = s_dumpE[kl];
        float aO = s_dumpO[kl - 1];
        int e0c = s_e0c, e1c = s_e1c;
        double sE = logTd + (double)((kl     >= 256) ? e1c : e0c) * LN2d;
        double sO = logTd + (double)((kl - 1 >= 256) ? e1c : e0c) * LN2d;
        double lE = (aE > 0.f) ? log((double)aE) - sE : -1e300;
        double lO = (aO > 0.f) ? log((double)aO) - sO : -1e300;
        double mx = fmax(lE, lO);
        double ll = (mx < -1e290) ? -745.0 : mx + log(exp(lE - mx) + exp(lO - mx));
        float val = (float)(-ll / ((double)kl * (double)BB));
        atomicAdd(out, val);
    }
}

extern "C" void kernel_launch(void* const* d_in, const int* in_sizes, int n_in,
                              void* d_out, int out_size, void* d_ws, size_t ws_size,
                              hipStream_t stream) {
    const float* attn     = (const float*)d_in[0];
    const int*   in_lens  = (const int*)d_in[1];
    const int*   out_lens = (const int*)d_in[2];
    float* out = (float*)d_out;
    hipMemsetAsync(out, 0, sizeof(float), stream);
    hipLaunchKernelGGL(ForwardSumLoss_77378130805413_kernel,
                       dim3(BB), dim3(NW * 64), 0, stream,
                       attn, in_lens, out_lens, out);
}